// Round 1
// baseline (350.504 us; speedup 1.0000x reference)
//
#include <hip/hip_runtime.h>

typedef __attribute__((ext_vector_type(8))) short bf16x8;
typedef __attribute__((ext_vector_type(4))) float f32x4;

// RNE float -> bf16
__device__ __forceinline__ unsigned short f2bf(float f) {
    union { float f; unsigned int u; } v; v.f = f;
    unsigned int r = v.u + 0x7FFFu + ((v.u >> 16) & 1u);
    return (unsigned short)(r >> 16);
}

// Unified tiled MLP: out_rows x 64 = relu( [A_gathered | B2] @ W^T + bias ),
// optionally scatter-added (atomic) into `out` via sidx, else stored directly.
//   A   : [*, 64] fp32, row chosen by gidx[e] (or e if gidx==null)
//   B2  : [rows, 64] fp32 (second half of the 128-wide input)
//   W   : [64, 128] fp32 row-major (torch Linear weight)
//   out : fp32; if sidx: Z[n,64] accumulated atomically; else [rows,64] stored
__global__ __launch_bounds__(256)
void gnn_mlp(const float* __restrict__ A,
             const float* __restrict__ B2,
             const int* __restrict__ gidx,
             const int* __restrict__ sidx,
             const float* __restrict__ W,
             const float* __restrict__ bias,
             float* __restrict__ out,
             int rows, int ntiles)
{
    // A-tile staged as bf16 [64 rows][128 k], XOR-swizzled to kill the
    // 16-way bank conflict of 256B-stride ds_read_b128 (guide §6 G4).
    __shared__ char Ab[64 * 128 * 2];

    const int t    = threadIdx.x;
    const int wave = t >> 6;
    const int lane = t & 63;
    const int lrow = lane & 15;          // MFMA fragment row/col index
    const int lko  = (lane >> 4) * 8;    // k sub-offset (elements) within 32-k step
    const int lko2 = lko * 2;            // ... in bytes

    // --- B fragments in registers: bfrag[f][ks] covers cols f*16..f*16+15, k = ks*32..+31
    bf16x8 bfrag[4][4];
#pragma unroll
    for (int f = 0; f < 4; ++f) {
#pragma unroll
        for (int ks = 0; ks < 4; ++ks) {
            const float* wp = W + (f * 16 + lrow) * 128 + ks * 32 + lko;
            bf16x8 v;
#pragma unroll
            for (int i = 0; i < 8; ++i)
                ((unsigned short*)&v)[i] = f2bf(wp[i]);
            bfrag[f][ks] = v;
        }
    }

    float bia[4];
#pragma unroll
    for (int f = 0; f < 4; ++f) bia[f] = bias[f * 16 + lrow];

    // staging assignment: thread -> (row el, quarter q); 8 float4 chunks each
    const int el = t >> 2;
    const int q  = t & 3;
    const int swz_w = (el & 7) << 4;

    for (int tile = blockIdx.x; tile < ntiles; tile += gridDim.x) {
        __syncthreads();  // previous iteration's reads of Ab are done
        {
            const long long e = (long long)tile * 64 + el;
            const bool ok = e < (long long)rows;
            long long arow = 0;
            if (ok) arow = gidx ? (long long)gidx[e] : e;
            const float* ap = A  + arow * 64;
            const float* bp = B2 + e * 64;
#pragma unroll
            for (int i = 0; i < 8; ++i) {
                const int c = q + 4 * i;      // chunk id 0..31, k0 = c*4
                float4 v = make_float4(0.f, 0.f, 0.f, 0.f);
                if (ok) v = (c < 16) ? *(const float4*)(ap + c * 4)
                                     : *(const float4*)(bp + (c - 16) * 4);
                unsigned int lo = (unsigned int)f2bf(v.x) | ((unsigned int)f2bf(v.y) << 16);
                unsigned int hi = (unsigned int)f2bf(v.z) | ((unsigned int)f2bf(v.w) << 16);
                *(uint2*)(Ab + ((el * 256 + c * 8) ^ swz_w)) = make_uint2(lo, hi);
            }
        }
        __syncthreads();

        // --- MFMA: wave w computes rows w*16..w*16+15, all 64 cols
        f32x4 acc[4] = {{0.f,0.f,0.f,0.f},{0.f,0.f,0.f,0.f},
                        {0.f,0.f,0.f,0.f},{0.f,0.f,0.f,0.f}};
        const int arl   = wave * 16 + lrow;
        const int rbase = arl * 256;
        const int swz_r = (arl & 7) << 4;
#pragma unroll
        for (int ks = 0; ks < 4; ++ks) {
            bf16x8 a = *(const bf16x8*)(Ab + ((rbase + ks * 64 + lko2) ^ swz_r));
#pragma unroll
            for (int f = 0; f < 4; ++f)
                acc[f] = __builtin_amdgcn_mfma_f32_16x16x32_bf16(a, bfrag[f][ks], acc[f], 0, 0, 0);
        }

        // --- epilogue: C layout col=lane&15, row=(lane>>4)*4+reg (guide §3, m89)
        const long long erow0 = (long long)tile * 64 + wave * 16 + (lane >> 4) * 4;
#pragma unroll
        for (int r = 0; r < 4; ++r) {
            const long long e = erow0 + r;
            if (e < (long long)rows) {
                if (sidx) {
                    const long long d = (long long)sidx[e] * 64;
#pragma unroll
                    for (int f = 0; f < 4; ++f)
                        atomicAdd(out + d + f * 16 + lrow,
                                  fmaxf(acc[f][r] + bia[f], 0.f));
                } else {
                    const long long o = e * 64;
#pragma unroll
                    for (int f = 0; f < 4; ++f)
                        out[o + f * 16 + lrow] = fmaxf(acc[f][r] + bia[f], 0.f);
                }
            }
        }
    }
}

extern "C" void kernel_launch(void* const* d_in, const int* in_sizes, int n_in,
                              void* d_out, int out_size, void* d_ws, size_t ws_size,
                              hipStream_t stream)
{
    const float* H   = (const float*)d_in[0];
    const float* Xe  = (const float*)d_in[1];
    const int*   idx = (const int*)d_in[2];   // [2, E]: row 0 = src, row 1 = dst
    const float* M_W = (const float*)d_in[3];
    const float* M_b = (const float*)d_in[4];
    const float* U_W = (const float*)d_in[5];
    const float* U_b = (const float*)d_in[6];
    float* Hn = (float*)d_out;
    float* Z  = (float*)d_ws;                 // [N, 64] fp32 scratch

    const int n_nodes = out_size / 64;
    const int n_edges = in_sizes[1] / 64;

    hipMemsetAsync(Z, 0, (size_t)n_nodes * 64 * sizeof(float), stream);

    const int etiles = (n_edges + 63) / 64;
    gnn_mlp<<<1024, 256, 0, stream>>>(H, Xe, idx, idx + n_edges,
                                      M_W, M_b, Z, n_edges, etiles);

    const int ntiles = (n_nodes + 63) / 64;
    gnn_mlp<<<ntiles, 256, 0, stream>>>(H, Z, nullptr, nullptr,
                                        U_W, U_b, Hn, n_nodes, ntiles);
}